// Round 1
// baseline (804.986 us; speedup 1.0000x reference)
//
#include <hip/hip_runtime.h>

// LSTM: B=8192, T=168, P=16, H=24, gate order [i,f,g,o].
// Strategy: 8 lanes per batch element (3 hidden units / 12 gate rows per lane),
// fused W = [W_hh | W_ih] (96x40) in LDS, h broadcast via __shfl within the
// 8-lane group (no per-step barrier), x prefetched one step ahead.
// 65536 threads = 1024 waves = 1 wave/SIMD over 256 CUs.

#define T_STEPS 168
#define P_FEAT  16
#define H_SZ    24

__device__ __forceinline__ float rcp_fast(float x) {
#if __has_builtin(__builtin_amdgcn_rcpf)
    return __builtin_amdgcn_rcpf(x);
#else
    return 1.0f / x;
#endif
}

__device__ __forceinline__ float exp2_fast(float x) {
#if __has_builtin(__builtin_amdgcn_exp2f)
    return __builtin_amdgcn_exp2f(x);
#else
    return exp2f(x);
#endif
}

__device__ __forceinline__ float sigmoid_f(float x) {
    // 1 / (1 + 2^(-x*log2(e)))
    return rcp_fast(1.0f + exp2_fast(x * -1.44269504f));
}

__device__ __forceinline__ float tanh_f(float x) {
    // 1 - 2 / (2^(2x*log2(e)) + 1); saturates correctly at +/-inf
    return 1.0f - 2.0f * rcp_fast(1.0f + exp2_fast(x * 2.88539008f));
}

__global__ __launch_bounds__(256, 1) void lstm_fused(
    const float* __restrict__ x,
    const float* __restrict__ W_ih,
    const float* __restrict__ W_hh,
    const float* __restrict__ b_ih,
    const float* __restrict__ b_hh,
    const float* __restrict__ W_lin,
    const float* __restrict__ b_lin,
    float* __restrict__ out)
{
    // Fused weights: row j (gate row, 0..95) = [W_hh[j][0..23], W_ih[j][0..15]]
    // stride 40 floats: ds_read_b128 across the 8 lanes of a group lands
    // 2-way bank aliasing (free) + 8-way broadcast across groups.
    __shared__ __align__(16) float Wlds[96 * 40];

    const int tid = threadIdx.x;
    for (int idx = tid; idx < 96 * 40; idx += 256) {
        const int j = idx / 40;
        const int k = idx - j * 40;
        Wlds[idx] = (k < 24) ? W_hh[j * 24 + k] : W_ih[j * 16 + (k - 24)];
    }
    __syncthreads();

    const int grp   = tid >> 3;        // 0..31: batch group within block
    const int r     = tid & 7;         // 0..7 : lane within group
    const int lane  = tid & 63;        // lane within wave
    const int sbase = lane & ~7;       // first lane of this group in the wave
    const int batch = blockIdx.x * 32 + grp;
    const int j0    = 3 * r;           // first hidden unit owned by this lane

    // 12 gate rows per lane: q = u*4 + gate, row = gate*24 + (j0+u)
    int   rowoff[12];
    float bias[12];
    #pragma unroll
    for (int u = 0; u < 3; u++) {
        #pragma unroll
        for (int gt = 0; gt < 4; gt++) {
            const int q  = u * 4 + gt;
            const int jj = gt * 24 + j0 + u;
            rowoff[q] = jj * 40;
            bias[q]   = b_ih[jj] + b_hh[jj];
        }
    }

    // hx = [h(24) | x_t(16)], fully register-resident
    float hx[40];
    #pragma unroll
    for (int k = 0; k < 24; k++) hx[k] = 0.0f;
    float cc[3] = {0.0f, 0.0f, 0.0f};

    const float* xb = x + (size_t)batch * (T_STEPS * P_FEAT);
    const float4* xv = reinterpret_cast<const float4*>(xb);
    float4 xf0 = xv[0], xf1 = xv[1], xf2 = xv[2], xf3 = xv[3];

    for (int t = 0; t < T_STEPS; t++) {
        hx[24] = xf0.x; hx[25] = xf0.y; hx[26] = xf0.z; hx[27] = xf0.w;
        hx[28] = xf1.x; hx[29] = xf1.y; hx[30] = xf1.z; hx[31] = xf1.w;
        hx[32] = xf2.x; hx[33] = xf2.y; hx[34] = xf2.z; hx[35] = xf2.w;
        hx[36] = xf3.x; hx[37] = xf3.y; hx[38] = xf3.z; hx[39] = xf3.w;

        // prefetch next step's x (uniform branch; hides global latency)
        if (t + 1 < T_STEPS) {
            const float4* xn = reinterpret_cast<const float4*>(xb + (t + 1) * P_FEAT);
            xf0 = xn[0]; xf1 = xn[1]; xf2 = xn[2]; xf3 = xn[3];
        }

        // 12 independent 40-long dot products (480 FMA, 120 ds_read_b128)
        float a[12];
        #pragma unroll
        for (int q = 0; q < 12; q++) a[q] = bias[q];

        #pragma unroll
        for (int kk = 0; kk < 40; kk += 4) {
            const float h0 = hx[kk + 0], h1 = hx[kk + 1];
            const float h2 = hx[kk + 2], h3 = hx[kk + 3];
            #pragma unroll
            for (int q = 0; q < 12; q++) {
                const float4 w = *reinterpret_cast<const float4*>(&Wlds[rowoff[q] + kk]);
                a[q] = fmaf(w.x, h0, a[q]);
                a[q] = fmaf(w.y, h1, a[q]);
                a[q] = fmaf(w.z, h2, a[q]);
                a[q] = fmaf(w.w, h3, a[q]);
            }
        }

        // nonlinearities + state update for own 3 units
        float hn[3];
        #pragma unroll
        for (int u = 0; u < 3; u++) {
            const float ig = sigmoid_f(a[u * 4 + 0]);
            const float fg = sigmoid_f(a[u * 4 + 1]);
            const float gg = tanh_f   (a[u * 4 + 2]);
            const float og = sigmoid_f(a[u * 4 + 3]);
            cc[u] = fg * cc[u] + ig * gg;
            hn[u] = og * tanh_f(cc[u]);
        }

        // rebroadcast full h[24] to every lane of the group (intra-wave)
        #pragma unroll
        for (int s = 0; s < 8; s++) {
            hx[3 * s + 0] = __shfl(hn[0], sbase + s, 64);
            hx[3 * s + 1] = __shfl(hn[1], sbase + s, 64);
            hx[3 * s + 2] = __shfl(hn[2], sbase + s, 64);
        }
    }

    // head: out[b][j] = b_lin[j] + sum_k tanh(h[k]) * W_lin[j][k]
    float th[24];
    #pragma unroll
    for (int k = 0; k < 24; k++) th[k] = tanh_f(hx[k]);

    #pragma unroll
    for (int u = 0; u < 3; u++) {
        const int jj = j0 + u;
        float acc = b_lin[jj];
        #pragma unroll
        for (int k = 0; k < 24; k++)
            acc = fmaf(th[k], W_lin[jj * 24 + k], acc);
        out[batch * 24 + jj] = acc;
    }
}

extern "C" void kernel_launch(void* const* d_in, const int* in_sizes, int n_in,
                              void* d_out, int out_size, void* d_ws, size_t ws_size,
                              hipStream_t stream) {
    const float* x     = (const float*)d_in[0];
    const float* W_ih  = (const float*)d_in[1];
    const float* W_hh  = (const float*)d_in[2];
    const float* b_ih  = (const float*)d_in[3];
    const float* b_hh  = (const float*)d_in[4];
    const float* W_lin = (const float*)d_in[5];
    const float* b_lin = (const float*)d_in[6];
    float* out = (float*)d_out;

    const int B = in_sizes[0] / (T_STEPS * P_FEAT);   // 8192
    dim3 grid(B / 32), block(256);                    // 32 batches/block, 8 lanes each
    lstm_fused<<<grid, block, 0, stream>>>(x, W_ih, W_hh, b_ih, b_hh, W_lin, b_lin, out);
}

// Round 2
// 327.195 us; speedup vs baseline: 2.4603x; 2.4603x over previous
//
#include <hip/hip_runtime.h>

// LSTM B=8192, T=168, P=16, H=24, gates [i,f,g,o].
// Round-2 design: WEIGHTS IN REGISTERS, STATE THROUGH LDS.
//  - 32 lanes per batch; lane j<24 owns unit j: all 4 gate rows = 160 fp32 in VGPRs.
//  - Per step: read hx (h[24] from hbuf, x[16] from LDS x-stage) as 10 ds_read_b128
//    (broadcast within batch), 160 FMAs, 5 transcendentals, write 1 h value back.
//  - Batch never crosses a wave -> NO __syncthreads in the T loop (same-wave DS
//    ops are processed in order; __builtin_amdgcn_wave_barrier stops compiler
//    reordering).
//  - x staged per-wave in 56-step chunks (3 chunks), coalesced float4 loads.
//  - 262144 threads = 4096 waves; VGPR budget ~220 -> 2 waves/SIMD.

#define T_STEPS 168
#define P_FEAT  16
#define H_SZ    24
#define CHUNK   56   // T_STEPS / 3

__device__ __forceinline__ float rcp_fast(float x) {
#if __has_builtin(__builtin_amdgcn_rcpf)
    return __builtin_amdgcn_rcpf(x);
#else
    return 1.0f / x;
#endif
}
__device__ __forceinline__ float exp2_fast(float x) {
#if __has_builtin(__builtin_amdgcn_exp2f)
    return __builtin_amdgcn_exp2f(x);
#else
    return exp2f(x);
#endif
}
__device__ __forceinline__ float sigmoid_f(float x) {
    return rcp_fast(1.0f + exp2_fast(x * -1.44269504f));
}
__device__ __forceinline__ float tanh_f(float x) {
    return 1.0f - 2.0f * rcp_fast(1.0f + exp2_fast(x * 2.88539008f));
}

__global__ __launch_bounds__(256, 2) void lstm_regw(
    const float* __restrict__ x,
    const float* __restrict__ W_ih,
    const float* __restrict__ W_hh,
    const float* __restrict__ b_ih,
    const float* __restrict__ b_hh,
    const float* __restrict__ W_lin,
    const float* __restrict__ b_lin,
    float* __restrict__ out)
{
    // LDS: fused weight stage (one-time), W_lin stage, x chunks, h state.
    __shared__ __align__(16) float Wlds[96 * 40];        // 15360 B, [row][ h(24) | x(16) ]
    __shared__ __align__(16) float WlinLds[24 * 24];     //  2304 B
    __shared__ __align__(16) float xs[8][CHUNK][16];     // 28672 B, per-block 8 batches
    __shared__ __align__(16) float hbuf[8][32];          //  1024 B (24 used, pad to 32)

    const int tid = threadIdx.x;

    // one-time weight staging (coalesced), then a single barrier
    for (int idx = tid; idx < 96 * 40; idx += 256) {
        const int j = idx / 40;
        const int k = idx - j * 40;
        Wlds[idx] = (k < 24) ? W_hh[j * 24 + k] : W_ih[j * 16 + (k - 24)];
    }
    for (int idx = tid; idx < 24 * 24; idx += 256) WlinLds[idx] = W_lin[idx];
    __syncthreads();

    const int wave = tid >> 6;            // 0..3
    const int lane = tid & 63;
    const int half = lane >> 5;           // which batch within the wave
    const int l    = lane & 31;           // 0..31 within batch group
    const bool active = (l < 24);
    const int j    = active ? l : 23;     // owned hidden unit (clamped for idle lanes)
    const int bb   = wave * 2 + half;     // 0..7 batch slot in block
    const int batch = blockIdx.x * 8 + bb;

    // pull this lane's 4 gate rows (i,f,g,o of unit j) into registers: 160 fp32
    float4 wv[4][10];
    float bias[4];
    #pragma unroll
    for (int g = 0; g < 4; g++) {
        const float* wrow = &Wlds[(g * 24 + j) * 40];
        #pragma unroll
        for (int kk = 0; kk < 10; kk++)
            wv[g][kk] = *reinterpret_cast<const float4*>(wrow + 4 * kk);
        bias[g] = b_ih[g * 24 + j] + b_hh[g * 24 + j];
    }

    // init state
    float c = 0.0f, hcur = 0.0f;
    if (active) hbuf[bb][j] = 0.0f;
    __builtin_amdgcn_wave_barrier();

    // x chunk staging: per wave, 2 batches x CHUNK steps x 16 floats = 448 float4
    const float4* xsrc = reinterpret_cast<const float4*>(x)
                       + (size_t)(blockIdx.x * 8 + wave * 2) * (T_STEPS * P_FEAT / 4);
    float4* xdst = reinterpret_cast<float4*>(&xs[wave * 2][0][0]);

    for (int cix = 0; cix < 3; cix++) {
        // load 448 float4 (7 per lane): coalesced global -> LDS
        #pragma unroll
        for (int i = 0; i < 7; i++) {
            const int m   = lane + 64 * i;          // 0..447
            const int bm  = (m >= 224) ? 1 : 0;     // which of the 2 batches
            const int rem = m - bm * 224;
            xdst[m] = xsrc[(size_t)bm * (T_STEPS * P_FEAT / 4) + cix * (CHUNK * P_FEAT / 4) + rem];
        }
        __builtin_amdgcn_wave_barrier();

        for (int t = 0; t < CHUNK; t++) {
            const float* hrow = &hbuf[bb][0];
            const float* xrow = &xs[bb][t][0];

            float a0 = bias[0], a1 = bias[1], a2 = bias[2], a3 = bias[3];

            // h part: k = 0..23
            #pragma unroll
            for (int kk = 0; kk < 6; kk++) {
                const float4 h4 = *reinterpret_cast<const float4*>(hrow + 4 * kk);
                a0 = fmaf(wv[0][kk].x, h4.x, a0); a0 = fmaf(wv[0][kk].y, h4.y, a0);
                a0 = fmaf(wv[0][kk].z, h4.z, a0); a0 = fmaf(wv[0][kk].w, h4.w, a0);
                a1 = fmaf(wv[1][kk].x, h4.x, a1); a1 = fmaf(wv[1][kk].y, h4.y, a1);
                a1 = fmaf(wv[1][kk].z, h4.z, a1); a1 = fmaf(wv[1][kk].w, h4.w, a1);
                a2 = fmaf(wv[2][kk].x, h4.x, a2); a2 = fmaf(wv[2][kk].y, h4.y, a2);
                a2 = fmaf(wv[2][kk].z, h4.z, a2); a2 = fmaf(wv[2][kk].w, h4.w, a2);
                a3 = fmaf(wv[3][kk].x, h4.x, a3); a3 = fmaf(wv[3][kk].y, h4.y, a3);
                a3 = fmaf(wv[3][kk].z, h4.z, a3); a3 = fmaf(wv[3][kk].w, h4.w, a3);
            }
            // x part: k = 24..39 (wv index 6..9)
            #pragma unroll
            for (int kk = 0; kk < 4; kk++) {
                const float4 x4 = *reinterpret_cast<const float4*>(xrow + 4 * kk);
                a0 = fmaf(wv[0][6 + kk].x, x4.x, a0); a0 = fmaf(wv[0][6 + kk].y, x4.y, a0);
                a0 = fmaf(wv[0][6 + kk].z, x4.z, a0); a0 = fmaf(wv[0][6 + kk].w, x4.w, a0);
                a1 = fmaf(wv[1][6 + kk].x, x4.x, a1); a1 = fmaf(wv[1][6 + kk].y, x4.y, a1);
                a1 = fmaf(wv[1][6 + kk].z, x4.z, a1); a1 = fmaf(wv[1][6 + kk].w, x4.w, a1);
                a2 = fmaf(wv[2][6 + kk].x, x4.x, a2); a2 = fmaf(wv[2][6 + kk].y, x4.y, a2);
                a2 = fmaf(wv[2][6 + kk].z, x4.z, a2); a2 = fmaf(wv[2][6 + kk].w, x4.w, a2);
                a3 = fmaf(wv[3][6 + kk].x, x4.x, a3); a3 = fmaf(wv[3][6 + kk].y, x4.y, a3);
                a3 = fmaf(wv[3][6 + kk].z, x4.z, a3); a3 = fmaf(wv[3][6 + kk].w, x4.w, a3);
            }

            const float ig = sigmoid_f(a0);
            const float fg = sigmoid_f(a1);
            const float gg = tanh_f(a2);
            const float og = sigmoid_f(a3);
            c = fg * c + ig * gg;
            hcur = og * tanh_f(c);

            if (active) hbuf[bb][j] = hcur;
            __builtin_amdgcn_wave_barrier();   // keep compiler from sinking reads above the write
        }
    }

    // head: out[b][j] = b_lin[j] + sum_k tanh(h[k]) * W_lin[j][k]
    if (active) hbuf[bb][j] = tanh_f(hcur);
    __builtin_amdgcn_wave_barrier();

    if (active) {
        const float* th = &hbuf[bb][0];
        const float* wl = &WlinLds[j * 24];
        float acc = b_lin[j];
        #pragma unroll
        for (int kk = 0; kk < 6; kk++) {
            const float4 t4 = *reinterpret_cast<const float4*>(th + 4 * kk);
            const float4 w4 = *reinterpret_cast<const float4*>(wl + 4 * kk);
            acc = fmaf(t4.x, w4.x, acc);
            acc = fmaf(t4.y, w4.y, acc);
            acc = fmaf(t4.z, w4.z, acc);
            acc = fmaf(t4.w, w4.w, acc);
        }
        out[(size_t)batch * 24 + j] = acc;
    }
}

extern "C" void kernel_launch(void* const* d_in, const int* in_sizes, int n_in,
                              void* d_out, int out_size, void* d_ws, size_t ws_size,
                              hipStream_t stream) {
    const float* x     = (const float*)d_in[0];
    const float* W_ih  = (const float*)d_in[1];
    const float* W_hh  = (const float*)d_in[2];
    const float* b_ih  = (const float*)d_in[3];
    const float* b_hh  = (const float*)d_in[4];
    const float* W_lin = (const float*)d_in[5];
    const float* b_lin = (const float*)d_in[6];
    float* out = (float*)d_out;

    const int B = in_sizes[0] / (T_STEPS * P_FEAT);   // 8192
    dim3 grid(B / 8), block(256);                     // 8 batches/block, 32 lanes/batch
    lstm_regw<<<grid, block, 0, stream>>>(x, W_ih, W_hh, b_ih, b_hh, W_lin, b_lin, out);
}

// Round 3
// 307.645 us; speedup vs baseline: 2.6166x; 1.0635x over previous
//
#include <hip/hip_runtime.h>

// LSTM B=8192, T=168, P=16, H=24, gates [i,f,g,o].
// Round-3: round-2 structure + (a) weights PINNED into VGPRs via opaque asm
// (round-2 post-mortem: VGPR=108 proved the compiler rematerialized weight
// loads as 40 ds_read_b128/step with 8-way bank conflicts), (b) dot products
// as float2 packed FMA (v_pk_fma_f32 if profitable on gfx950; identical
// scalar FMAs otherwise).
//  - 32 lanes/batch; lane j<24 owns unit j (4 gate rows = 160 weight floats).
//  - Per step: 10 ds_read_b128 (h broadcast + x), 80 packed FMA, 5 trans.
//  - Batch confined to one wave -> no __syncthreads in T loop.

#define T_STEPS 168
#define P_FEAT  16
#define H_SZ    24
#define CHUNK   56   // T_STEPS / 3

typedef float f2 __attribute__((ext_vector_type(2)));

__device__ __forceinline__ float rcp_fast(float x) {
#if __has_builtin(__builtin_amdgcn_rcpf)
    return __builtin_amdgcn_rcpf(x);
#else
    return 1.0f / x;
#endif
}
__device__ __forceinline__ float exp2_fast(float x) {
#if __has_builtin(__builtin_amdgcn_exp2f)
    return __builtin_amdgcn_exp2f(x);
#else
    return exp2f(x);
#endif
}
__device__ __forceinline__ float sigmoid_f(float x) {
    return rcp_fast(1.0f + exp2_fast(x * -1.44269504f));
}
__device__ __forceinline__ float tanh_f(float x) {
    return 1.0f - 2.0f * rcp_fast(1.0f + exp2_fast(x * 2.88539008f));
}
__device__ __forceinline__ f2 fma2(f2 a, f2 b, f2 c) {
#if __has_builtin(__builtin_elementwise_fma)
    return __builtin_elementwise_fma(a, b, c);
#else
    return a * b + c;   // -ffp-contract=fast
#endif
}

__global__ __launch_bounds__(256, 2) void lstm_regw(
    const float* __restrict__ x,
    const float* __restrict__ W_ih,
    const float* __restrict__ W_hh,
    const float* __restrict__ b_ih,
    const float* __restrict__ b_hh,
    const float* __restrict__ W_lin,
    const float* __restrict__ b_lin,
    float* __restrict__ out)
{
    __shared__ __align__(16) float Wlds[96 * 40];        // [row][ h(24) | x(16) ]
    __shared__ __align__(16) float WlinLds[24 * 24];
    __shared__ __align__(16) float xs[8][CHUNK][16];     // 8 batches/block
    __shared__ __align__(16) float hbuf[8][32];

    const int tid = threadIdx.x;

    for (int idx = tid; idx < 96 * 40; idx += 256) {
        const int j = idx / 40;
        const int k = idx - j * 40;
        Wlds[idx] = (k < 24) ? W_hh[j * 24 + k] : W_ih[j * 16 + (k - 24)];
    }
    for (int idx = tid; idx < 24 * 24; idx += 256) WlinLds[idx] = W_lin[idx];
    __syncthreads();

    const int wave = tid >> 6;
    const int lane = tid & 63;
    const int half = lane >> 5;
    const int l    = lane & 31;
    const bool active = (l < 24);
    const int j    = active ? l : 23;
    const int bb   = wave * 2 + half;
    const int batch = blockIdx.x * 8 + bb;

    // this lane's 4 gate rows of unit j -> 80 float2 = 160 VGPRs, then PIN.
    f2 w2[4][20];
    float bias[4];
    #pragma unroll
    for (int g = 0; g < 4; g++) {
        const f2* wrow = reinterpret_cast<const f2*>(&Wlds[(g * 24 + j) * 40]);
        #pragma unroll
        for (int m = 0; m < 20; m++) w2[g][m] = wrow[m];
        bias[g] = b_ih[g * 24 + j] + b_hh[g * 24 + j];
    }
    // Opaque def: compiler cannot rematerialize these from LDS anymore.
    #pragma unroll
    for (int g = 0; g < 4; g++) {
        #pragma unroll
        for (int m = 0; m < 20; m++) {
            asm volatile("" : "+v"(w2[g][m]));
        }
    }

    float c = 0.0f, hcur = 0.0f;
    if (active) hbuf[bb][j] = 0.0f;
    __builtin_amdgcn_wave_barrier();

    const float4* xsrc = reinterpret_cast<const float4*>(x)
                       + (size_t)(blockIdx.x * 8 + wave * 2) * (T_STEPS * P_FEAT / 4);
    float4* xdst = reinterpret_cast<float4*>(&xs[wave * 2][0][0]);

    for (int cix = 0; cix < 3; cix++) {
        #pragma unroll
        for (int i = 0; i < 7; i++) {
            const int m   = lane + 64 * i;          // 0..447
            const int bm  = (m >= 224) ? 1 : 0;
            const int rem = m - bm * 224;
            xdst[m] = xsrc[(size_t)bm * (T_STEPS * P_FEAT / 4) + cix * (CHUNK * P_FEAT / 4) + rem];
        }
        __builtin_amdgcn_wave_barrier();

        const float* hrow = &hbuf[bb][0];
        const float* xrow0 = &xs[bb][0][0];

        for (int t = 0; t < CHUNK; t++) {
            const float* xrow = xrow0 + t * 16;

            f2 acc0 = {bias[0], 0.0f};
            f2 acc1 = {bias[1], 0.0f};
            f2 acc2 = {bias[2], 0.0f};
            f2 acc3 = {bias[3], 0.0f};

            #pragma unroll
            for (int kk = 0; kk < 10; kk++) {
                const float4 v = (kk < 6)
                    ? *reinterpret_cast<const float4*>(hrow + 4 * kk)
                    : *reinterpret_cast<const float4*>(xrow + 4 * (kk - 6));
                const f2 lo = {v.x, v.y};
                const f2 hi = {v.z, v.w};
                acc0 = fma2(w2[0][2 * kk], lo, acc0);
                acc0 = fma2(w2[0][2 * kk + 1], hi, acc0);
                acc1 = fma2(w2[1][2 * kk], lo, acc1);
                acc1 = fma2(w2[1][2 * kk + 1], hi, acc1);
                acc2 = fma2(w2[2][2 * kk], lo, acc2);
                acc2 = fma2(w2[2][2 * kk + 1], hi, acc2);
                acc3 = fma2(w2[3][2 * kk], lo, acc3);
                acc3 = fma2(w2[3][2 * kk + 1], hi, acc3);
            }

            const float ig = sigmoid_f(acc0.x + acc0.y);
            const float fg = sigmoid_f(acc1.x + acc1.y);
            const float gg = tanh_f   (acc2.x + acc2.y);
            const float og = sigmoid_f(acc3.x + acc3.y);
            c = fg * c + ig * gg;
            hcur = og * tanh_f(c);

            if (active) hbuf[bb][j] = hcur;
            __builtin_amdgcn_wave_barrier();
        }
    }

    if (active) hbuf[bb][j] = tanh_f(hcur);
    __builtin_amdgcn_wave_barrier();

    if (active) {
        const float* th = &hbuf[bb][0];
        const float* wl = &WlinLds[j * 24];
        float acc = b_lin[j];
        #pragma unroll
        for (int kk = 0; kk < 6; kk++) {
            const float4 t4 = *reinterpret_cast<const float4*>(th + 4 * kk);
            const float4 w4 = *reinterpret_cast<const float4*>(wl + 4 * kk);
            acc = fmaf(t4.x, w4.x, acc);
            acc = fmaf(t4.y, w4.y, acc);
            acc = fmaf(t4.z, w4.z, acc);
            acc = fmaf(t4.w, w4.w, acc);
        }
        out[(size_t)batch * 24 + j] = acc;
    }
}

extern "C" void kernel_launch(void* const* d_in, const int* in_sizes, int n_in,
                              void* d_out, int out_size, void* d_ws, size_t ws_size,
                              hipStream_t stream) {
    const float* x     = (const float*)d_in[0];
    const float* W_ih  = (const float*)d_in[1];
    const float* W_hh  = (const float*)d_in[2];
    const float* b_ih  = (const float*)d_in[3];
    const float* b_hh  = (const float*)d_in[4];
    const float* W_lin = (const float*)d_in[5];
    const float* b_lin = (const float*)d_in[6];
    float* out = (float*)d_out;

    const int B = in_sizes[0] / (T_STEPS * P_FEAT);   // 8192
    dim3 grid(B / 8), block(256);                     // 8 batches/block, 32 lanes/batch
    lstm_regw<<<grid, block, 0, stream>>>(x, W_ih, W_hh, b_ih, b_hh, W_lin, b_lin, out);
}

// Round 4
// 286.173 us; speedup vs baseline: 2.8129x; 1.0750x over previous
//
#include <hip/hip_runtime.h>

// LSTM B=8192, T=168, P=16, H=24, gates [i,f,g,o].
// Round-4: f16 weights + f16 hx with v_dot2_f32_f16 (fp32 accumulate).
//  - Round-3 post-mortem: 160 fp32 weight regs -> allocator split 112 arch +
//    ~144 AGPR, ~160 AGPR<->VGPR copies per step (VALUBusy math matched).
//  - f16 halves weights to 80 regs (fits 128-reg budget at 4 waves/SIMD),
//    halves MAC issue (80 dot2/step), halves LDS reads (5 ds_read_b128/step).
//  - 32 lanes/batch, lane j<24 owns unit j (4 gate rows); batch confined to
//    one wave -> no __syncthreads in T loop.
//  - 1024 blocks x 256 thr = 4 blocks/CU, whole grid resident in one round.

#define T_STEPS 168
#define P_FEAT  16
#define H_SZ    24
#define CHUNK   56   // T_STEPS / 3

typedef _Float16 h2 __attribute__((ext_vector_type(2)));

__device__ __forceinline__ float rcp_fast(float x) {
#if __has_builtin(__builtin_amdgcn_rcpf)
    return __builtin_amdgcn_rcpf(x);
#else
    return 1.0f / x;
#endif
}
__device__ __forceinline__ float exp2_fast(float x) {
#if __has_builtin(__builtin_amdgcn_exp2f)
    return __builtin_amdgcn_exp2f(x);
#else
    return exp2f(x);
#endif
}
__device__ __forceinline__ float sigmoid_f(float x) {
    return rcp_fast(1.0f + exp2_fast(x * -1.44269504f));
}
__device__ __forceinline__ float tanh_f(float x) {
    return 1.0f - 2.0f * rcp_fast(1.0f + exp2_fast(x * 2.88539008f));
}
__device__ __forceinline__ float dot2(h2 a, h2 b, float c) {
#if __has_builtin(__builtin_amdgcn_fdot2)
    return __builtin_amdgcn_fdot2(a, b, c, false);
#else
    return fmaf((float)a.x, (float)b.x, fmaf((float)a.y, (float)b.y, c));
#endif
}
__device__ __forceinline__ h2 pack2(float a, float b) {
    h2 r; r.x = (_Float16)a; r.y = (_Float16)b; return r;
}

__global__ __launch_bounds__(256, 4) void lstm_f16(
    const float* __restrict__ x,
    const float* __restrict__ W_ih,
    const float* __restrict__ W_hh,
    const float* __restrict__ b_ih,
    const float* __restrict__ b_hh,
    const float* __restrict__ W_lin,
    const float* __restrict__ b_lin,
    float* __restrict__ out)
{
    __shared__ __align__(16) float    Wlds[96 * 40];      // 15360 B [row][h24|x16]
    __shared__ __align__(16) float    WlinLds[24 * 24];   //  2304 B
    __shared__ __align__(16) _Float16 xs16[8][CHUNK][16]; // 14336 B
    __shared__ __align__(16) _Float16 hbuf16[8][32];      //   512 B (24 used)
    __shared__ __align__(16) float    thbuf[8][32];       //  1024 B
    // total ~33.5 KB -> 4 blocks/CU fits (134 KB of 160 KB)

    const int tid = threadIdx.x;

    for (int idx = tid; idx < 96 * 40; idx += 256) {
        const int j = idx / 40;
        const int k = idx - j * 40;
        Wlds[idx] = (k < 24) ? W_hh[j * 24 + k] : W_ih[j * 16 + (k - 24)];
    }
    for (int idx = tid; idx < 24 * 24; idx += 256) WlinLds[idx] = W_lin[idx];
    __syncthreads();

    const int wave = tid >> 6;
    const int lane = tid & 63;
    const int half = lane >> 5;
    const int l    = lane & 31;
    const bool active = (l < 24);
    const int j    = active ? l : 23;
    const int bb   = wave * 2 + half;
    const int batch = blockIdx.x * 8 + bb;

    // 4 gate rows of unit j as f16 pairs: 80 regs. Pair m covers hx[2m,2m+1].
    h2 wf[4][20];
    float bias[4];
    #pragma unroll
    for (int g = 0; g < 4; g++) {
        const float* wrow = &Wlds[(g * 24 + j) * 40];
        #pragma unroll
        for (int m = 0; m < 20; m++) wf[g][m] = pack2(wrow[2 * m], wrow[2 * m + 1]);
        bias[g] = b_ih[g * 24 + j] + b_hh[g * 24 + j];
    }
    // opaque pin: no remat-from-LDS
    #pragma unroll
    for (int g = 0; g < 4; g++) {
        #pragma unroll
        for (int m = 0; m < 20; m++) asm volatile("" : "+v"(wf[g][m]));
    }

    float c = 0.0f, hcur = 0.0f;
    if (active) hbuf16[bb][j] = (_Float16)0.0f;
    __builtin_amdgcn_wave_barrier();

    const float4* xsrc = reinterpret_cast<const float4*>(x)
                       + (size_t)(blockIdx.x * 8 + wave * 2) * (T_STEPS * P_FEAT / 4);
    h2* xdst = reinterpret_cast<h2*>(&xs16[wave * 2][0][0]);

    for (int cix = 0; cix < 3; cix++) {
        // stage 2 batches x 56 steps x 16 floats -> f16 (7 float4 per lane)
        #pragma unroll
        for (int i = 0; i < 7; i++) {
            const int m   = lane + 64 * i;          // 0..447 float4 index
            const int bm  = (m >= 224) ? 1 : 0;
            const int rem = m - bm * 224;
            const float4 v = xsrc[(size_t)bm * (T_STEPS * P_FEAT / 4)
                                  + cix * (CHUNK * P_FEAT / 4) + rem];
            xdst[2 * m]     = pack2(v.x, v.y);
            xdst[2 * m + 1] = pack2(v.z, v.w);
        }
        __builtin_amdgcn_wave_barrier();

        const uint4* hrow = reinterpret_cast<const uint4*>(&hbuf16[bb][0]);
        const _Float16* xrow0 = &xs16[bb][0][0];

        for (int t = 0; t < CHUNK; t++) {
            // 5 ds_read_b128: h[24] (48B) + x[16] (32B), broadcast in group
            const uint4 hA = hrow[0];
            const uint4 hB = hrow[1];
            const uint4 hC = hrow[2];
            const uint4 xA = reinterpret_cast<const uint4*>(xrow0 + t * 16)[0];
            const uint4 xB = reinterpret_cast<const uint4*>(xrow0 + t * 16)[1];

            h2 hx2[20];
            hx2[0]  = __builtin_bit_cast(h2, hA.x); hx2[1]  = __builtin_bit_cast(h2, hA.y);
            hx2[2]  = __builtin_bit_cast(h2, hA.z); hx2[3]  = __builtin_bit_cast(h2, hA.w);
            hx2[4]  = __builtin_bit_cast(h2, hB.x); hx2[5]  = __builtin_bit_cast(h2, hB.y);
            hx2[6]  = __builtin_bit_cast(h2, hB.z); hx2[7]  = __builtin_bit_cast(h2, hB.w);
            hx2[8]  = __builtin_bit_cast(h2, hC.x); hx2[9]  = __builtin_bit_cast(h2, hC.y);
            hx2[10] = __builtin_bit_cast(h2, hC.z); hx2[11] = __builtin_bit_cast(h2, hC.w);
            hx2[12] = __builtin_bit_cast(h2, xA.x); hx2[13] = __builtin_bit_cast(h2, xA.y);
            hx2[14] = __builtin_bit_cast(h2, xA.z); hx2[15] = __builtin_bit_cast(h2, xA.w);
            hx2[16] = __builtin_bit_cast(h2, xB.x); hx2[17] = __builtin_bit_cast(h2, xB.y);
            hx2[18] = __builtin_bit_cast(h2, xB.z); hx2[19] = __builtin_bit_cast(h2, xB.w);

            float a0 = bias[0], a1 = bias[1], a2 = bias[2], a3 = bias[3];
            #pragma unroll
            for (int m = 0; m < 20; m++) {
                a0 = dot2(wf[0][m], hx2[m], a0);
                a1 = dot2(wf[1][m], hx2[m], a1);
                a2 = dot2(wf[2][m], hx2[m], a2);
                a3 = dot2(wf[3][m], hx2[m], a3);
            }

            const float ig = sigmoid_f(a0);
            const float fg = sigmoid_f(a1);
            const float gg = tanh_f(a2);
            const float og = sigmoid_f(a3);
            c = fg * c + ig * gg;
            hcur = og * tanh_f(c);

            if (active) hbuf16[bb][j] = (_Float16)hcur;
            __builtin_amdgcn_wave_barrier();
        }
    }

    // head in fp32: out[b][j] = b_lin[j] + sum_k tanh(h[k]) * W_lin[j][k]
    if (active) thbuf[bb][j] = tanh_f(hcur);
    __builtin_amdgcn_wave_barrier();

    if (active) {
        const float* th = &thbuf[bb][0];
        const float* wl = &WlinLds[j * 24];
        float acc = b_lin[j];
        #pragma unroll
        for (int kk = 0; kk < 6; kk++) {
            const float4 t4 = *reinterpret_cast<const float4*>(th + 4 * kk);
            const float4 w4 = *reinterpret_cast<const float4*>(wl + 4 * kk);
            acc = fmaf(t4.x, w4.x, acc);
            acc = fmaf(t4.y, w4.y, acc);
            acc = fmaf(t4.z, w4.z, acc);
            acc = fmaf(t4.w, w4.w, acc);
        }
        out[(size_t)batch * 24 + j] = acc;
    }
}

extern "C" void kernel_launch(void* const* d_in, const int* in_sizes, int n_in,
                              void* d_out, int out_size, void* d_ws, size_t ws_size,
                              hipStream_t stream) {
    const float* x     = (const float*)d_in[0];
    const float* W_ih  = (const float*)d_in[1];
    const float* W_hh  = (const float*)d_in[2];
    const float* b_ih  = (const float*)d_in[3];
    const float* b_hh  = (const float*)d_in[4];
    const float* W_lin = (const float*)d_in[5];
    const float* b_lin = (const float*)d_in[6];
    float* out = (float*)d_out;

    const int B = in_sizes[0] / (T_STEPS * P_FEAT);   // 8192
    dim3 grid(B / 8), block(256);                     // 8 batches/block, 32 lanes/batch
    lstm_f16<<<grid, block, 0, stream>>>(x, W_ih, W_hh, b_ih, b_hh, W_lin, b_lin, out);
}

// Round 5
// 285.379 us; speedup vs baseline: 2.8208x; 1.0028x over previous
//
#include <hip/hip_runtime.h>

// LSTM B=8192, T=168, P=16, H=24, gates [i,f,g,o].
// Round-5: identical to round-4 except __launch_bounds__(256,3).
//  - r4 post-mortem: VGPR_Count=64 proved the 128-reg budget at 4 waves/EU
//    forced a 64 arch + 64 AGPR split -> ~80 v_accvgpr_read copies per step
//    (VALU 270 instr/lane-step vs ~110 ideal). Budget 170 at 3 waves/EU fits
//    the whole live set (80 f16x2 weights + 20 hx2 + accums) in arch VGPRs.
//  - Structure is DS-throughput-bound (~80 us floor: 6 DS instr/lane-step);
//    total DS instr is residency-invariant, so 12 waves/CU loses nothing.
//  - 32 lanes/batch, lane j<24 owns unit j (4 gate rows as 20 f16x2 regs);
//    per step: 5 ds_read_b128 (h24+x16 f16, group-broadcast), 80 v_dot2,
//    5 transcendentals, 1 ds_write_b16. Batch confined to one wave -> no
//    __syncthreads in the T loop.

#define T_STEPS 168
#define P_FEAT  16
#define H_SZ    24
#define CHUNK   56   // T_STEPS / 3

typedef _Float16 h2 __attribute__((ext_vector_type(2)));

__device__ __forceinline__ float rcp_fast(float x) {
#if __has_builtin(__builtin_amdgcn_rcpf)
    return __builtin_amdgcn_rcpf(x);
#else
    return 1.0f / x;
#endif
}
__device__ __forceinline__ float exp2_fast(float x) {
#if __has_builtin(__builtin_amdgcn_exp2f)
    return __builtin_amdgcn_exp2f(x);
#else
    return exp2f(x);
#endif
}
__device__ __forceinline__ float sigmoid_f(float x) {
    return rcp_fast(1.0f + exp2_fast(x * -1.44269504f));
}
__device__ __forceinline__ float tanh_f(float x) {
    return 1.0f - 2.0f * rcp_fast(1.0f + exp2_fast(x * 2.88539008f));
}
__device__ __forceinline__ float dot2(h2 a, h2 b, float c) {
#if __has_builtin(__builtin_amdgcn_fdot2)
    return __builtin_amdgcn_fdot2(a, b, c, false);
#else
    return fmaf((float)a.x, (float)b.x, fmaf((float)a.y, (float)b.y, c));
#endif
}
__device__ __forceinline__ h2 pack2(float a, float b) {
    h2 r; r.x = (_Float16)a; r.y = (_Float16)b; return r;
}

__global__ __launch_bounds__(256, 3) void lstm_f16(
    const float* __restrict__ x,
    const float* __restrict__ W_ih,
    const float* __restrict__ W_hh,
    const float* __restrict__ b_ih,
    const float* __restrict__ b_hh,
    const float* __restrict__ W_lin,
    const float* __restrict__ b_lin,
    float* __restrict__ out)
{
    __shared__ __align__(16) float    Wlds[96 * 40];      // 15360 B [row][h24|x16]
    __shared__ __align__(16) float    WlinLds[24 * 24];   //  2304 B
    __shared__ __align__(16) _Float16 xs16[8][CHUNK][16]; // 14336 B
    __shared__ __align__(16) _Float16 hbuf16[8][32];      //   512 B (24 used)
    __shared__ __align__(16) float    thbuf[8][32];       //  1024 B

    const int tid = threadIdx.x;

    for (int idx = tid; idx < 96 * 40; idx += 256) {
        const int j = idx / 40;
        const int k = idx - j * 40;
        Wlds[idx] = (k < 24) ? W_hh[j * 24 + k] : W_ih[j * 16 + (k - 24)];
    }
    for (int idx = tid; idx < 24 * 24; idx += 256) WlinLds[idx] = W_lin[idx];
    __syncthreads();

    const int wave = tid >> 6;
    const int lane = tid & 63;
    const int half = lane >> 5;
    const int l    = lane & 31;
    const bool active = (l < 24);
    const int j    = active ? l : 23;
    const int bb   = wave * 2 + half;
    const int batch = blockIdx.x * 8 + bb;

    // 4 gate rows of unit j as f16 pairs: 80 regs. Pair m covers hx[2m,2m+1].
    h2 wf[4][20];
    float bias[4];
    #pragma unroll
    for (int g = 0; g < 4; g++) {
        const float* wrow = &Wlds[(g * 24 + j) * 40];
        #pragma unroll
        for (int m = 0; m < 20; m++) wf[g][m] = pack2(wrow[2 * m], wrow[2 * m + 1]);
        bias[g] = b_ih[g * 24 + j] + b_hh[g * 24 + j];
    }
    // opaque pin: no remat-from-LDS
    #pragma unroll
    for (int g = 0; g < 4; g++) {
        #pragma unroll
        for (int m = 0; m < 20; m++) asm volatile("" : "+v"(wf[g][m]));
    }

    float c = 0.0f, hcur = 0.0f;
    if (active) hbuf16[bb][j] = (_Float16)0.0f;
    __builtin_amdgcn_wave_barrier();

    const float4* xsrc = reinterpret_cast<const float4*>(x)
                       + (size_t)(blockIdx.x * 8 + wave * 2) * (T_STEPS * P_FEAT / 4);
    h2* xdst = reinterpret_cast<h2*>(&xs16[wave * 2][0][0]);

    for (int cix = 0; cix < 3; cix++) {
        // stage 2 batches x 56 steps x 16 floats -> f16 (7 float4 per lane)
        #pragma unroll
        for (int i = 0; i < 7; i++) {
            const int m   = lane + 64 * i;          // 0..447 float4 index
            const int bm  = (m >= 224) ? 1 : 0;
            const int rem = m - bm * 224;
            const float4 v = xsrc[(size_t)bm * (T_STEPS * P_FEAT / 4)
                                  + cix * (CHUNK * P_FEAT / 4) + rem];
            xdst[2 * m]     = pack2(v.x, v.y);
            xdst[2 * m + 1] = pack2(v.z, v.w);
        }
        __builtin_amdgcn_wave_barrier();

        const uint4* hrow = reinterpret_cast<const uint4*>(&hbuf16[bb][0]);
        const _Float16* xrow0 = &xs16[bb][0][0];

        for (int t = 0; t < CHUNK; t++) {
            // 5 ds_read_b128: h[24] (48B) + x[16] (32B), broadcast in group
            const uint4 hA = hrow[0];
            const uint4 hB = hrow[1];
            const uint4 hC = hrow[2];
            const uint4 xA = reinterpret_cast<const uint4*>(xrow0 + t * 16)[0];
            const uint4 xB = reinterpret_cast<const uint4*>(xrow0 + t * 16)[1];

            h2 hx2[20];
            hx2[0]  = __builtin_bit_cast(h2, hA.x); hx2[1]  = __builtin_bit_cast(h2, hA.y);
            hx2[2]  = __builtin_bit_cast(h2, hA.z); hx2[3]  = __builtin_bit_cast(h2, hA.w);
            hx2[4]  = __builtin_bit_cast(h2, hB.x); hx2[5]  = __builtin_bit_cast(h2, hB.y);
            hx2[6]  = __builtin_bit_cast(h2, hB.z); hx2[7]  = __builtin_bit_cast(h2, hB.w);
            hx2[8]  = __builtin_bit_cast(h2, hC.x); hx2[9]  = __builtin_bit_cast(h2, hC.y);
            hx2[10] = __builtin_bit_cast(h2, hC.z); hx2[11] = __builtin_bit_cast(h2, hC.w);
            hx2[12] = __builtin_bit_cast(h2, xA.x); hx2[13] = __builtin_bit_cast(h2, xA.y);
            hx2[14] = __builtin_bit_cast(h2, xA.z); hx2[15] = __builtin_bit_cast(h2, xA.w);
            hx2[16] = __builtin_bit_cast(h2, xB.x); hx2[17] = __builtin_bit_cast(h2, xB.y);
            hx2[18] = __builtin_bit_cast(h2, xB.z); hx2[19] = __builtin_bit_cast(h2, xB.w);

            float a0 = bias[0], a1 = bias[1], a2 = bias[2], a3 = bias[3];
            #pragma unroll
            for (int m = 0; m < 20; m++) {
                a0 = dot2(wf[0][m], hx2[m], a0);
                a1 = dot2(wf[1][m], hx2[m], a1);
                a2 = dot2(wf[2][m], hx2[m], a2);
                a3 = dot2(wf[3][m], hx2[m], a3);
            }

            const float ig = sigmoid_f(a0);
            const float fg = sigmoid_f(a1);
            const float gg = tanh_f(a2);
            const float og = sigmoid_f(a3);
            c = fg * c + ig * gg;
            hcur = og * tanh_f(c);

            if (active) hbuf16[bb][j] = (_Float16)hcur;
            __builtin_amdgcn_wave_barrier();
        }
    }

    // head in fp32: out[b][j] = b_lin[j] + sum_k tanh(h[k]) * W_lin[j][k]
    if (active) thbuf[bb][j] = tanh_f(hcur);
    __builtin_amdgcn_wave_barrier();

    if (active) {
        const float* th = &thbuf[bb][0];
        const float* wl = &WlinLds[j * 24];
        float acc = b_lin[j];
        #pragma unroll
        for (int kk = 0; kk < 6; kk++) {
            const float4 t4 = *reinterpret_cast<const float4*>(th + 4 * kk);
            const float4 w4 = *reinterpret_cast<const float4*>(wl + 4 * kk);
            acc = fmaf(t4.x, w4.x, acc);
            acc = fmaf(t4.y, w4.y, acc);
            acc = fmaf(t4.z, w4.z, acc);
            acc = fmaf(t4.w, w4.w, acc);
        }
        out[(size_t)batch * 24 + j] = acc;
    }
}

extern "C" void kernel_launch(void* const* d_in, const int* in_sizes, int n_in,
                              void* d_out, int out_size, void* d_ws, size_t ws_size,
                              hipStream_t stream) {
    const float* x     = (const float*)d_in[0];
    const float* W_ih  = (const float*)d_in[1];
    const float* W_hh  = (const float*)d_in[2];
    const float* b_ih  = (const float*)d_in[3];
    const float* b_hh  = (const float*)d_in[4];
    const float* W_lin = (const float*)d_in[5];
    const float* b_lin = (const float*)d_in[6];
    float* out = (float*)d_out;

    const int B = in_sizes[0] / (T_STEPS * P_FEAT);   // 8192
    dim3 grid(B / 8), block(256);                     // 8 batches/block, 32 lanes/batch
    lstm_f16<<<grid, block, 0, stream>>>(x, W_ih, W_hh, b_ih, b_hh, W_lin, b_lin, out);
}

// Round 6
// 253.510 us; speedup vs baseline: 3.1754x; 1.1257x over previous
//
#include <hip/hip_runtime.h>

// LSTM B=8192, T=168, P=16, H=24, gates [i,f,g,o].
// Round-6: MFMA rewrite. gates[96] = [W_hh|W_ih] @ [h|x] batched 16/wave via
// v_mfma_f32_16x16x32_f16: 6 m-tiles x 2 K-chunks = 12 MFMA/step (vs 80 dot2).
//  - r3-r5 post-mortem: allocator parks big register sets in AGPRs and VALU
//    pays a copy per use; MFMA reads AGPRs natively -> tax structurally gone.
//  - Gate-row PERMUTATION: tile position p holds gate p%4 of unit (p/4)*6+mt,
//    so C-layout (row=quad*4+r, col=lane&15) gives each lane ALL 4 gates of
//    unit quad*6+mt for batch lane&15 -> zero cross-lane exchange.
//  - K-chunk1 = h[24]+8 zeros (hpad), chunk2 = x_t[16]+16 zeros (xs16).
//    B-frag: one ds_read_b128 each (quads beyond data get zeros).
//  - 512 blocks x 64 threads (1 wave, 16 batches); 2 blocks/CU; x staged f16
//    in 2 chunks of 84 steps (43 KB); weight stage reused/overwritten by x
//    staging = natural register pin.

#define T_STEPS 168
#define P_FEAT  16
#define H_SZ    24
#define TCH     84    // t-chunk length
#define NB      16    // batches per wave

typedef _Float16 half8 __attribute__((ext_vector_type(8)));
typedef _Float16 h2    __attribute__((ext_vector_type(2)));
typedef float    f32x4 __attribute__((ext_vector_type(4)));

__device__ __forceinline__ float rcp_fast(float x) {
#if __has_builtin(__builtin_amdgcn_rcpf)
    return __builtin_amdgcn_rcpf(x);
#else
    return 1.0f / x;
#endif
}
__device__ __forceinline__ float exp2_fast(float x) {
#if __has_builtin(__builtin_amdgcn_exp2f)
    return __builtin_amdgcn_exp2f(x);
#else
    return exp2f(x);
#endif
}
__device__ __forceinline__ float sigmoid_f(float x) {
    return rcp_fast(1.0f + exp2_fast(x * -1.44269504f));
}
__device__ __forceinline__ float tanh_f(float x) {
    return 1.0f - 2.0f * rcp_fast(1.0f + exp2_fast(x * 2.88539008f));
}
__device__ __forceinline__ h2 pack2(float a, float b) {
    h2 r; r.x = (_Float16)a; r.y = (_Float16)b; return r;
}

__global__ __launch_bounds__(64, 1) void lstm_mfma(
    const float* __restrict__ x,
    const float* __restrict__ W_ih,
    const float* __restrict__ W_hh,
    const float* __restrict__ b_ih,
    const float* __restrict__ b_hh,
    const float* __restrict__ W_lin,
    const float* __restrict__ b_lin,
    float* __restrict__ out)
{
    __shared__ __align__(16) _Float16 xs16[NB][TCH][16];  // 43008 B (f16 x chunk)
    __shared__ __align__(16) _Float16 hpad[NB][32];       //  1024 B: h[24] + 8 zeros
    __shared__ __align__(16) float    thbuf[NB][24];      //  1536 B (epilogue)

    const int lane = threadIdx.x;   // 0..63, one wave per block
    const int n    = lane & 15;     // batch column
    const int quad = lane >> 4;     // 0..3

    // ---- one-time: stage fused W (f32) into xs16 space, coalesced ----
    float* wstage = reinterpret_cast<float*>(&xs16[0][0][0]);  // 96*40 floats = 15360 B
    for (int idx = lane; idx < 96 * 40; idx += 64) {
        const int j = idx / 40;
        const int k = idx - j * 40;
        wstage[idx] = (k < 24) ? W_hh[j * 24 + k] : W_ih[j * 16 + (k - 24)];
    }
    __builtin_amdgcn_wave_barrier();

    // ---- build A-fragments (permuted rows) + bias C-fragments ----
    // matrix-row position p of tile mt = gate (p%4) of unit (p/4)*6+mt.
    // A-frag: lane supplies row m=lane&15, k=quad*8+j  [m120 layout]
    half8 A1[6], A2[6];
    f32x4 biasf[6];
    #pragma unroll
    for (int mt = 0; mt < 6; mt++) {
        const int grow = (n & 3) * 24 + (n >> 2) * 6 + mt;  // permuted gate row
        #pragma unroll
        for (int j = 0; j < 8; j++) {
            const int k = quad * 8 + j;                     // 0..31
            A1[mt][j] = (k < 24) ? (_Float16)wstage[grow * 40 + k] : (_Float16)0.0f;
            A2[mt][j] = (k < 16) ? (_Float16)wstage[grow * 40 + 24 + k] : (_Float16)0.0f;
        }
        #pragma unroll
        for (int r = 0; r < 4; r++) {
            const int row = r * 24 + quad * 6 + mt;         // gate r of unit quad*6+mt
            biasf[mt][r] = b_ih[row] + b_hh[row];
        }
    }
    __builtin_amdgcn_wave_barrier();   // wstage dead after this; x staging reuses it

    // ---- init h state: hpad = 0 (incl. padding halves 24..31, kept 0 forever)
    *reinterpret_cast<uint4*>(reinterpret_cast<char*>(&hpad[0][0]) + lane * 16) =
        uint4{0, 0, 0, 0};
    __builtin_amdgcn_wave_barrier();

    float c[6] = {0, 0, 0, 0, 0, 0};
    float hreg[6];

    const float4* xsrc = reinterpret_cast<const float4*>(x)
                       + (size_t)(blockIdx.x * NB) * (T_STEPS * P_FEAT / 4);

    for (int ch = 0; ch < 2; ch++) {
        // stage NB batches x TCH steps x 16 floats -> f16 (5376 float4, 84/lane)
        for (int i = 0; i < TCH; i++) {
            const int m   = lane + 64 * i;      // 0..5375
            const int b   = m / 336;            // 336 float4 per batch-chunk
            const int rem = m - b * 336;
            const float4 v = xsrc[(size_t)b * (T_STEPS * P_FEAT / 4) + ch * 336 + rem];
            h2* dst = reinterpret_cast<h2*>(&xs16[0][0][0] + b * (TCH * 16) + rem * 4);
            dst[0] = pack2(v.x, v.y);
            dst[1] = pack2(v.z, v.w);
        }
        __builtin_amdgcn_wave_barrier();

        for (int t = 0; t < TCH; t++) {
            // B-frags: k=quad*8+j.  B1: [h(24)|0(8)];  B2: [x(16)|0(16)]
            const half8 B1 = *reinterpret_cast<const half8*>(&hpad[n][quad * 8]);
            half8 B2 = {};
            if (quad < 2) B2 = *reinterpret_cast<const half8*>(&xs16[n][t][quad * 8]);

            f32x4 g[6];
            #pragma unroll
            for (int mt = 0; mt < 6; mt++) {
                f32x4 tmp = __builtin_amdgcn_mfma_f32_16x16x32_f16(A1[mt], B1, biasf[mt], 0, 0, 0);
                g[mt]     = __builtin_amdgcn_mfma_f32_16x16x32_f16(A2[mt], B2, tmp,      0, 0, 0);
            }

            // lane owns ALL 4 gates of units quad*6+mt (mt=0..5), batch n
            #pragma unroll
            for (int mt = 0; mt < 6; mt++) {
                const float ig = sigmoid_f(g[mt][0]);
                const float fg = sigmoid_f(g[mt][1]);
                const float gg = tanh_f   (g[mt][2]);
                const float og = sigmoid_f(g[mt][3]);
                c[mt]    = fg * c[mt] + ig * gg;
                hreg[mt] = og * tanh_f(c[mt]);
            }

            // write h: 6 consecutive units at hpad[n][quad*6] (3 x ds_write_b32)
            *reinterpret_cast<h2*>(&hpad[n][quad * 6 + 0]) = pack2(hreg[0], hreg[1]);
            *reinterpret_cast<h2*>(&hpad[n][quad * 6 + 2]) = pack2(hreg[2], hreg[3]);
            *reinterpret_cast<h2*>(&hpad[n][quad * 6 + 4]) = pack2(hreg[4], hreg[5]);
            __builtin_amdgcn_wave_barrier();
        }
    }

    // ---- epilogue: out[b][j] = b_lin[j] + sum_k tanh(h[k]) * W_lin[j][k] ----
    #pragma unroll
    for (int s = 0; s < 6; s++) thbuf[n][quad * 6 + s] = tanh_f(hreg[s]);
    __builtin_amdgcn_wave_barrier();

    float th[24];
    #pragma unroll
    for (int kk = 0; kk < 6; kk++) {
        const f32x4 t4 = *reinterpret_cast<const f32x4*>(&thbuf[n][4 * kk]);
        th[4 * kk + 0] = t4[0]; th[4 * kk + 1] = t4[1];
        th[4 * kk + 2] = t4[2]; th[4 * kk + 3] = t4[3];
    }
    const int batch = blockIdx.x * NB + n;
    #pragma unroll
    for (int s = 0; s < 6; s++) {
        const int j = quad * 6 + s;
        const float* wl = &W_lin[j * 24];
        float acc = b_lin[j];
        #pragma unroll
        for (int k = 0; k < 24; k++) acc = fmaf(th[k], wl[k], acc);
        out[(size_t)batch * 24 + j] = acc;
    }
}

extern "C" void kernel_launch(void* const* d_in, const int* in_sizes, int n_in,
                              void* d_out, int out_size, void* d_ws, size_t ws_size,
                              hipStream_t stream) {
    const float* x     = (const float*)d_in[0];
    const float* W_ih  = (const float*)d_in[1];
    const float* W_hh  = (const float*)d_in[2];
    const float* b_ih  = (const float*)d_in[3];
    const float* b_hh  = (const float*)d_in[4];
    const float* W_lin = (const float*)d_in[5];
    const float* b_lin = (const float*)d_in[6];
    float* out = (float*)d_out;

    const int B = in_sizes[0] / (T_STEPS * P_FEAT);   // 8192
    dim3 grid(B / NB), block(64);                     // 512 waves, 16 batches each
    lstm_mfma<<<grid, block, 0, stream>>>(x, W_ih, W_hh, b_ih, b_hh, W_lin, b_lin, out);
}